// Round 8
// baseline (123.453 us; speedup 1.0000x reference)
//
#include <hip/hip_runtime.h>
#include <math.h>

#define TEMP 0.01f

typedef __attribute__((ext_vector_type(8))) short short8;
typedef __attribute__((ext_vector_type(4))) float f32x4;
typedef __attribute__((ext_vector_type(8))) unsigned short ushort8_t;

// ---------------------------------------------------------------------------
// ws layout (floats from base):
//   nsum   f32[4096] @ 0
//   nmaxb  i32[4096] @ 4096
//   pcw    f32[4096] @ 8192
//   pcwl   f32[4096] @ 12288
//   accum  f32[3]    @ 16384, counter int @ 16387
//   posbuf f32[4096*128] @ 16400 (ends at float 540688)
//   Ph     ushort[4096*128] @ float 540688  (bf16-hi plane, LINEAR layout)
//   Pl     ushort[4096*128] after Ph        (bf16-lo plane)
// needs 4,259,904 bytes (ws proven >= this in rounds 5/7).
// ---------------------------------------------------------------------------

__device__ __forceinline__ unsigned bf16_hi_bits(float x) {
  unsigned u = __float_as_uint(x);
  return (u + 0x7FFFu + ((u >> 16) & 1u)) >> 16;  // RNE to bf16
}

struct HL { unsigned short h, l; };

__device__ __forceinline__ HL split1(float x) {
  unsigned hb = bf16_hi_bits(x);
  float hf = __uint_as_float(hb << 16);
  unsigned lb = bf16_hi_bits(x - hf);
  HL r;
  r.h = (unsigned short)hb;
  r.l = (unsigned short)lb;
  return r;
}

__device__ __forceinline__ void decode_ov(const int* __restrict__ ov_raw,
                                          int* s_class2, int* s_v2b,
                                          int* s_ov) {
  const int t = threadIdx.x;
  if (t < 64) {
    int v = (t < 32) ? ov_raw[t] : 0;
    bool valid = (t >= 32) || (v == 0) || (v == 1);
    unsigned long long okmask = __ballot(valid);
    bool as_int = (okmask == ~0ull);
    s_v2b[t] = 0;
    if (t < 32) {
      int o = as_int ? v : (((const unsigned char*)ov_raw)[t] ? 1 : 0);
      s_ov[t] = o;
      unsigned long long nz = __ballot((t < 32) && !o);
      int cum = __popcll(nz & ((1ull << t) - 1ull));
      int c2 = o ? t : 32 + cum;
      s_class2[t] = c2;
      s_v2b[c2] = t;
    }
  }
}

__device__ __forceinline__ int labf(int g, const int* s_class2) {
  return (g < 2048) ? (g >> 6) : s_class2[(g - 2048) >> 6];
}

__device__ __forceinline__ int slotf(int g, int cls, const int* s_v2b) {
  if (g < 2048) return g - (cls << 6);
  return ((cls < 32) ? 64 : 0) + (g - 2048 - (s_v2b[cls] << 6));
}

// ---------------------------------------------------------------------------
// Precompute: split all 4096 rows into bf16 hi/lo planes, LINEAR k layout
// (Ph[row*128 + k] = hi bits of feats[row][k]).
// ---------------------------------------------------------------------------
__global__ __launch_bounds__(256) void precompute_kernel(
    const float* __restrict__ f1, const float* __restrict__ f2,
    unsigned short* __restrict__ Ph, unsigned short* __restrict__ Pl) {
  const int u = blockIdx.x * 256 + threadIdx.x;  // 65536 threads
  const int row = u >> 4;
  const int seg = u & 15;
  const int k = seg * 8;
  const float* src = (row < 2048) ? (f1 + (size_t)row * 128)
                                  : (f2 + (size_t)(row - 2048) * 128);
  const float4 a = *(const float4*)(src + k);
  const float4 b = *(const float4*)(src + k + 4);
  ushort8_t hi, lo;
  HL s;
  s = split1(a.x); hi.s0 = s.h; lo.s0 = s.l;
  s = split1(a.y); hi.s1 = s.h; lo.s1 = s.l;
  s = split1(a.z); hi.s2 = s.h; lo.s2 = s.l;
  s = split1(a.w); hi.s3 = s.h; lo.s3 = s.l;
  s = split1(b.x); hi.s4 = s.h; lo.s4 = s.l;
  s = split1(b.y); hi.s5 = s.h; lo.s5 = s.l;
  s = split1(b.z); hi.s6 = s.h; lo.s6 = s.l;
  s = split1(b.w); hi.s7 = s.h; lo.s7 = s.l;
  *(ushort8_t*)&Ph[(size_t)row * 128 + k] = hi;
  *(ushort8_t*)&Pl[(size_t)row * 128 + k] = lo;
}

// ---------------------------------------------------------------------------
// No-LDS main: 528 triangular 128x128 tiles, one per block, 4 waves in 2x2.
// MFMA fragments are contiguous 16B granules in the precomputed planes —
// loaded straight from L2 (planes = 2 MB, L2-resident). No __syncthreads in
// the K-loop, no staging; occupancy capped only by VGPRs (4 blocks/CU) so
// all 528 blocks run in ONE generation. MFMA order identical to rounds 4-7
// (bit-identical numerics).
// ---------------------------------------------------------------------------
__global__ __launch_bounds__(256, 4) void main_kernel(
    const unsigned short* __restrict__ Ph, const unsigned short* __restrict__ Pl,
    const int* __restrict__ ov_raw, float* __restrict__ nsum,
    int* __restrict__ nmaxb, float* __restrict__ pcw,
    float* __restrict__ pcwl, float* __restrict__ posbuf) {
  __shared__ int s_class2[32], s_v2b[64], s_ov[32];

  decode_ov(ov_raw, s_class2, s_v2b, s_ov);
  __syncthreads();  // only barrier in the kernel

  // triangular decode incl. diagonal: row bi has 32-bi tiles (bj >= bi)
  int idx = blockIdx.x, bi = 0;
  while (idx >= 32 - bi) { idx -= 32 - bi; ++bi; }
  const int bj = bi + idx;
  const bool diag = (bi == bj);
  const int ibase = bi * 128, jbase = bj * 128;

  const int t = threadIdx.x;
  const int l = t & 63;
  const int wid = t >> 6;
  const int wy = wid >> 1, wx = wid & 1;
  const int rr = l & 15;
  const int q = l >> 4;

  // fragment base pointers (lane-fixed): row = base + tile*16 + rr,
  // in-row ushort offset = ks*32 + q*8
  const unsigned short* PA = Ph + ((size_t)(ibase + wy * 64 + rr) << 7) + q * 8;
  const unsigned short* LA = Pl + ((size_t)(ibase + wy * 64 + rr) << 7) + q * 8;
  const unsigned short* PB = Ph + ((size_t)(jbase + wx * 64 + rr) << 7) + q * 8;
  const unsigned short* LB = Pl + ((size_t)(jbase + wx * 64 + rr) << 7) + q * 8;

  f32x4 acc[4][4];
#pragma unroll
  for (int mi = 0; mi < 4; ++mi)
#pragma unroll
    for (int ni = 0; ni < 4; ++ni) acc[mi][ni] = (f32x4)0.0f;

#pragma unroll
  for (int ks = 0; ks < 4; ++ks) {  // K chunks of 32
    const int ko = ks * 32;
    short8 bfh[4], bfl[4];
#pragma unroll
    for (int ni = 0; ni < 4; ++ni) {
      bfh[ni] = *(const short8*)(PB + ni * 2048 + ko);
      bfl[ni] = *(const short8*)(LB + ni * 2048 + ko);
    }
#pragma unroll
    for (int mi = 0; mi < 4; ++mi) {
      const short8 afh = *(const short8*)(PA + mi * 2048 + ko);
      const short8 afl = *(const short8*)(LA + mi * 2048 + ko);
#pragma unroll
      for (int ni = 0; ni < 4; ++ni) {
        acc[mi][ni] = __builtin_amdgcn_mfma_f32_16x16x32_bf16(
            afh, bfh[ni], acc[mi][ni], 0, 0, 0);
        acc[mi][ni] = __builtin_amdgcn_mfma_f32_16x16x32_bf16(
            afh, bfl[ni], acc[mi][ni], 0, 0, 0);
        acc[mi][ni] = __builtin_amdgcn_mfma_f32_16x16x32_bf16(
            afl, bfh[ni], acc[mi][ni], 0, 0, 0);
      }
    }
  }

  // ---------------- fused epilogue (row + transposed col stats) ----------
  const bool off = !diag;
  const float cw = ((ibase < 2048) != (jbase < 2048)) ? 0.5f : 1.0f;
  int gj[4], lj[4];
#pragma unroll
  for (int ni = 0; ni < 4; ++ni) {
    gj[ni] = jbase + wx * 64 + ni * 16 + rr;
    lj[ni] = labf(gj[ni], s_class2);
  }

  float cnsum[4], cnmax[4], cpcw[4], cpcwl[4];
#pragma unroll
  for (int ni = 0; ni < 4; ++ni) {
    cnsum[ni] = 0.f; cnmax[ni] = 0.f; cpcw[ni] = 0.f; cpcwl[ni] = 0.f;
  }

#pragma unroll
  for (int mi = 0; mi < 4; ++mi) {
#pragma unroll
    for (int reg = 0; reg < 4; ++reg) {
      const int gi = ibase + wy * 64 + mi * 16 + q * 4 + reg;
      const int li = labf(gi, s_class2);
      float rnsum = 0.f, rnmax = 0.f, rpcw = 0.f, rpcwl = 0.f;
#pragma unroll
      for (int ni = 0; ni < 4; ++ni) {
        const int gjj = gj[ni];
        if (gi == gjj) continue;
        const float logit = acc[mi][ni][reg] * TEMP;
        const float e = __expf(logit);
        if (li == lj[ni]) {
          rpcw += cw;
          rpcwl += cw * logit;
          posbuf[(size_t)gi * 128 + slotf(gjj, li, s_v2b)] = e;
          if (off) {
            cpcw[ni] += cw;
            cpcwl[ni] += cw * logit;
            posbuf[(size_t)gjj * 128 + slotf(gi, li, s_v2b)] = e;
          }
        } else {
          rnsum += e;
          rnmax = fmaxf(rnmax, e);
          if (off) {
            cnsum[ni] += e;
            cnmax[ni] = fmaxf(cnmax[ni], e);
          }
        }
      }
#pragma unroll
      for (int m = 1; m < 16; m <<= 1) {
        rnsum += __shfl_xor(rnsum, m, 64);
        rpcw  += __shfl_xor(rpcw, m, 64);
        rpcwl += __shfl_xor(rpcwl, m, 64);
        rnmax = fmaxf(rnmax, __shfl_xor(rnmax, m, 64));
      }
      if (rr == 0) {
        atomicAdd(&nsum[gi], rnsum);
        atomicAdd(&pcw[gi], rpcw);
        atomicAdd(&pcwl[gi], rpcwl);
        atomicMax(&nmaxb[gi], __float_as_int(rnmax));
      }
    }
  }

  if (off) {
#pragma unroll
    for (int ni = 0; ni < 4; ++ni) {
      float cs = cnsum[ni], cm = cnmax[ni], cp = cpcw[ni], cl = cpcwl[ni];
#pragma unroll
      for (int m = 16; m < 64; m <<= 1) {
        cs += __shfl_xor(cs, m, 64);
        cp += __shfl_xor(cp, m, 64);
        cl += __shfl_xor(cl, m, 64);
        cm = fmaxf(cm, __shfl_xor(cm, m, 64));
      }
      if (q == 0) {
        const int g = gj[ni];
        atomicAdd(&nsum[g], cs);
        atomicAdd(&pcw[g], cp);
        atomicAdd(&pcwl[g], cl);
        atomicMax(&nmaxb[g], __float_as_int(cm));
      }
    }
  }
}

// 64 blocks x 256; last block writes the 2 outputs.
__global__ __launch_bounds__(256) void finalize_kernel(
    const int* __restrict__ ov_raw, const float* __restrict__ nsum,
    const int* __restrict__ nmaxb, const float* __restrict__ pcw,
    const float* __restrict__ pcwl, const float* __restrict__ posbuf,
    float* __restrict__ accum, int* __restrict__ counter,
    float* __restrict__ out) {
  __shared__ int s_class2[32], s_v2b[64], s_ov[32];
  __shared__ float sc[4], sp[4], sl[4];
  decode_ov(ov_raw, s_class2, s_v2b, s_ov);
  __syncthreads();

  const int t = threadIdx.x;
  const int w = t >> 6, lane = t & 63;
  float cnt_acc = 0.f, pos_acc = 0.f, loss_acc = 0.f;
  const int rbase = blockIdx.x * 64 + w * 16;
  for (int i = 0; i < 16; ++i) {
    const int row = rbase + i;
    const float2 pv = *(const float2*)&posbuf[(size_t)row * 128 + lane * 2];
    const int c = labf(row, s_class2);
    const int size = (c < 32) ? (s_ov[c] ? 128 : 64) : 64;
    int selfslot;
    if (row < 2048) selfslot = row - (c << 6);
    else selfslot = ((c < 32) ? 64 : 0) + (row - 2048 - (s_v2b[c] << 6));
    const float nmax = __int_as_float(nmaxb[row]);
    const int s0 = lane * 2;
    int h = 0;
    if (s0 < size && s0 != selfslot && pv.x > nmax) h++;
    if (s0 + 1 < size && s0 + 1 != selfslot && pv.y > nmax) h++;
    cnt_acc += (float)h;
    if (lane == 0) {
      loss_acc += logf(nsum[row]) * pcw[row] - pcwl[row];
      pos_acc += (float)(size - 1);
    }
  }
#pragma unroll
  for (int m = 1; m < 64; m <<= 1) {
    cnt_acc += __shfl_xor(cnt_acc, m, 64);
    pos_acc += __shfl_xor(pos_acc, m, 64);
    loss_acc += __shfl_xor(loss_acc, m, 64);
  }
  if (lane == 0) { sc[w] = cnt_acc; sp[w] = pos_acc; sl[w] = loss_acc; }
  __syncthreads();
  if (t == 0) {
    atomicAdd(&accum[0], sc[0] + sc[1] + sc[2] + sc[3]);
    atomicAdd(&accum[1], sp[0] + sp[1] + sp[2] + sp[3]);
    atomicAdd(&accum[2], sl[0] + sl[1] + sl[2] + sl[3]);
    __threadfence();
    const int prev = atomicAdd(counter, 1);
    if (prev == 63) {
      const float c = atomicAdd(&accum[0], 0.0f);
      const float tp = atomicAdd(&accum[1], 0.0f);
      const float lo = atomicAdd(&accum[2], 0.0f);
      out[0] = c / tp;
      out[1] = lo / tp;
    }
  }
}

extern "C" void kernel_launch(void* const* d_in, const int* in_sizes, int n_in,
                              void* d_out, int out_size, void* d_ws,
                              size_t ws_size, hipStream_t stream) {
  const float* f1 = (const float*)d_in[0];
  const float* f2 = (const float*)d_in[1];
  const int* ov = (const int*)d_in[2];
  float* out = (float*)d_out;

  float* wsf = (float*)d_ws;
  int* wsi = (int*)d_ws;
  float* nsum   = wsf;            // 4096
  int* nmaxb    = wsi + 4096;     // 4096
  float* pcw    = wsf + 8192;     // 4096
  float* pcwl   = wsf + 12288;    // 4096
  float* accum  = wsf + 16384;    // 3
  int* counter  = wsi + 16387;    // 1
  float* posbuf = wsf + 16400;    // 4096*128 -> ends at float 540688
  unsigned short* Ph = (unsigned short*)(wsf + 540688);
  unsigned short* Pl = Ph + 524288;

  (void)hipMemsetAsync(nsum, 0, (size_t)16392 * sizeof(float), stream);

  precompute_kernel<<<256, 256, 0, stream>>>(f1, f2, Ph, Pl);
  main_kernel<<<528, 256, 0, stream>>>(Ph, Pl, ov, nsum, nmaxb, pcw, pcwl,
                                       posbuf);
  finalize_kernel<<<64, 256, 0, stream>>>(ov, nsum, nmaxb, pcw, pcwl, posbuf,
                                          accum, counter, out);
}

// Round 9
// 112.143 us; speedup vs baseline: 1.1009x; 1.1009x over previous
//
#include <hip/hip_runtime.h>
#include <math.h>

#define TEMP 0.01f

typedef __attribute__((ext_vector_type(8))) short short8;
typedef __attribute__((ext_vector_type(4))) float f32x4;
typedef __attribute__((ext_vector_type(8))) unsigned short ushort8_t;

// ---------------------------------------------------------------------------
// ws layout (floats from base):
//   accum  f32[3] @ 0, counter int @ 3          (memset 16 B only)
//   posbuf f32[4096*128] @ 16                   (per-row positive exp slots)
//   P4     float4[4096*64] @ float 524304       (per-row partial stats:
//            [row][other_tile*2 + half] = {nsum, pcw, pcwl, nmax};
//            every slot written by exactly one wave -> no init, NO ATOMICS)
//   Ph     ushort[4096*128] @ float 1572880     (bf16-hi plane, swizzled)
//   Pl     ushort[4096*128] after Ph            (bf16-lo plane)
// total ~8.4 MB (ws ~268 MB per harness fill).
// ---------------------------------------------------------------------------

__device__ __forceinline__ unsigned bf16_hi_bits(float x) {
  unsigned u = __float_as_uint(x);
  return (u + 0x7FFFu + ((u >> 16) & 1u)) >> 16;  // RNE to bf16
}

struct HL { unsigned short h, l; };

__device__ __forceinline__ HL split1(float x) {
  unsigned hb = bf16_hi_bits(x);
  float hf = __uint_as_float(hb << 16);
  unsigned lb = bf16_hi_bits(x - hf);
  HL r;
  r.h = (unsigned short)hb;
  r.l = (unsigned short)lb;
  return r;
}

__device__ __forceinline__ void decode_ov(const int* __restrict__ ov_raw,
                                          int* s_class2, int* s_v2b,
                                          int* s_ov) {
  const int t = threadIdx.x;
  if (t < 64) {
    int v = (t < 32) ? ov_raw[t] : 0;
    bool valid = (t >= 32) || (v == 0) || (v == 1);
    unsigned long long okmask = __ballot(valid);
    bool as_int = (okmask == ~0ull);
    s_v2b[t] = 0;
    if (t < 32) {
      int o = as_int ? v : (((const unsigned char*)ov_raw)[t] ? 1 : 0);
      s_ov[t] = o;
      unsigned long long nz = __ballot((t < 32) && !o);
      int cum = __popcll(nz & ((1ull << t) - 1ull));
      int c2 = o ? t : 32 + cum;
      s_class2[t] = c2;
      s_v2b[c2] = t;
    }
  }
}

__device__ __forceinline__ int labf(int g, const int* s_class2) {
  return (g < 2048) ? (g >> 6) : s_class2[(g - 2048) >> 6];
}

__device__ __forceinline__ int slotf(int g, int cls, const int* s_v2b) {
  if (g < 2048) return g - (cls << 6);
  return ((cls < 32) ? 64 : 0) + (g - 2048 - (s_v2b[cls] << 6));
}

// ---------------------------------------------------------------------------
// Precompute (round-7 proven): bf16 hi/lo planes, swizzle baked in:
// per row, per 64-K-chunk kc, physical granule P holds k = kc*64+(P^(row&7))*8.
// ---------------------------------------------------------------------------
__global__ __launch_bounds__(256) void precompute_kernel(
    const float* __restrict__ f1, const float* __restrict__ f2,
    unsigned short* __restrict__ Ph, unsigned short* __restrict__ Pl) {
  const int u = blockIdx.x * 256 + threadIdx.x;  // 65536 threads
  const int row = u >> 4;
  const int gid = u & 15;          // kc*8 + P
  const int kc = gid >> 3, P = gid & 7;
  const int k = kc * 64 + (P ^ (row & 7)) * 8;
  const float* src = (row < 2048) ? (f1 + (size_t)row * 128)
                                  : (f2 + (size_t)(row - 2048) * 128);
  const float4 a = *(const float4*)(src + k);
  const float4 b = *(const float4*)(src + k + 4);
  ushort8_t hi, lo;
  HL s;
  s = split1(a.x); hi.s0 = s.h; lo.s0 = s.l;
  s = split1(a.y); hi.s1 = s.h; lo.s1 = s.l;
  s = split1(a.z); hi.s2 = s.h; lo.s2 = s.l;
  s = split1(a.w); hi.s3 = s.h; lo.s3 = s.l;
  s = split1(b.x); hi.s4 = s.h; lo.s4 = s.l;
  s = split1(b.y); hi.s5 = s.h; lo.s5 = s.l;
  s = split1(b.z); hi.s6 = s.h; lo.s6 = s.l;
  s = split1(b.w); hi.s7 = s.h; lo.s7 = s.l;
  *(ushort8_t*)&Ph[(size_t)row * 128 + gid * 8] = hi;
  *(ushort8_t*)&Pl[(size_t)row * 128 + gid * 8] = lo;
}

// ---------------------------------------------------------------------------
// One 128x128 tile — round-7 proven K-loop; commits are plain float4 stores
// into P4 (no atomics anywhere in this kernel).
// ---------------------------------------------------------------------------
__device__ __forceinline__ void compute_tile(
    int bi, int bj, bool diag,
    const unsigned short* __restrict__ Ph, const unsigned short* __restrict__ Pl,
    unsigned short (*Ah)[64], unsigned short (*Al)[64],
    unsigned short (*Bh)[64], unsigned short (*Bl)[64],
    const int* s_class2, const int* s_v2b,
    float4* __restrict__ P4, float* __restrict__ posbuf) {
  const int ibase = bi * 128, jbase = bj * 128;
  const int t = threadIdx.x;
  const int l = t & 63;
  const int wid = t >> 6;
  const int wy = wid >> 1, wx = wid & 1;
  const int rr = l & 15;
  const int q = l >> 4;
  const int sw = l & 7;

  f32x4 acc[4][4];
#pragma unroll
  for (int mi = 0; mi < 4; ++mi)
#pragma unroll
    for (int ni = 0; ni < 4; ++ni) acc[mi][ni] = (f32x4)0.0f;

  const int gg = t & 7;    // physical granule
  const int r0 = t >> 3;   // row 0..31 per pass

  for (int kc = 0; kc < 2; ++kc) {
    __syncthreads();
#pragma unroll
    for (int p = 0; p < 4; ++p) {
      const int r = r0 + 32 * p;
      const size_t arec = (size_t)(ibase + r) * 128 + kc * 64 + gg * 8;
      const ushort8_t vah = *(const ushort8_t*)&Ph[arec];
      const ushort8_t val = *(const ushort8_t*)&Pl[arec];
      *(ushort8_t*)&Ah[r][gg * 8] = vah;
      *(ushort8_t*)&Al[r][gg * 8] = val;
      if (!diag) {
        const size_t brec = (size_t)(jbase + r) * 128 + kc * 64 + gg * 8;
        const ushort8_t vbh = *(const ushort8_t*)&Ph[brec];
        const ushort8_t vbl = *(const ushort8_t*)&Pl[brec];
        *(ushort8_t*)&Bh[r][gg * 8] = vbh;
        *(ushort8_t*)&Bl[r][gg * 8] = vbl;
      }
    }
    __syncthreads();

#pragma unroll
    for (int s = 0; s < 2; ++s) {
      const int pb = ((((s << 2) | q)) ^ sw) << 3;
      short8 afh[4], afl[4], bfh[4], bfl[4];
#pragma unroll
      for (int mi = 0; mi < 4; ++mi) {
        const int ar = wy * 64 + mi * 16 + rr;
        afh[mi] = *(const short8*)&Ah[ar][pb];
        afl[mi] = *(const short8*)&Al[ar][pb];
        const int br = wx * 64 + mi * 16 + rr;
        bfh[mi] = diag ? *(const short8*)&Ah[br][pb]
                       : *(const short8*)&Bh[br][pb];
        bfl[mi] = diag ? *(const short8*)&Al[br][pb]
                       : *(const short8*)&Bl[br][pb];
      }
#pragma unroll
      for (int mi = 0; mi < 4; ++mi)
#pragma unroll
        for (int ni = 0; ni < 4; ++ni) {
          acc[mi][ni] = __builtin_amdgcn_mfma_f32_16x16x32_bf16(
              afh[mi], bfh[ni], acc[mi][ni], 0, 0, 0);
          acc[mi][ni] = __builtin_amdgcn_mfma_f32_16x16x32_bf16(
              afh[mi], bfl[ni], acc[mi][ni], 0, 0, 0);
          acc[mi][ni] = __builtin_amdgcn_mfma_f32_16x16x32_bf16(
              afl[mi], bfh[ni], acc[mi][ni], 0, 0, 0);
        }
    }
  }

  // ---------------- fused epilogue: partial stores, no atomics ------------
  const bool off = !diag;
  const float cw = ((ibase < 2048) != (jbase < 2048)) ? 0.5f : 1.0f;
  int gj[4], lj[4];
#pragma unroll
  for (int ni = 0; ni < 4; ++ni) {
    gj[ni] = jbase + wx * 64 + ni * 16 + rr;
    lj[ni] = labf(gj[ni], s_class2);
  }

  float cnsum[4], cnmax[4], cpcw[4], cpcwl[4];
#pragma unroll
  for (int ni = 0; ni < 4; ++ni) {
    cnsum[ni] = 0.f; cnmax[ni] = 0.f; cpcw[ni] = 0.f; cpcwl[ni] = 0.f;
  }

#pragma unroll
  for (int mi = 0; mi < 4; ++mi) {
#pragma unroll
    for (int reg = 0; reg < 4; ++reg) {
      const int gi = ibase + wy * 64 + mi * 16 + q * 4 + reg;
      const int li = labf(gi, s_class2);
      float rnsum = 0.f, rnmax = 0.f, rpcw = 0.f, rpcwl = 0.f;
#pragma unroll
      for (int ni = 0; ni < 4; ++ni) {
        const int gjj = gj[ni];
        if (gi == gjj) continue;
        const float logit = acc[mi][ni][reg] * TEMP;
        const float e = __expf(logit);
        if (li == lj[ni]) {
          rpcw += cw;
          rpcwl += cw * logit;
          posbuf[(size_t)gi * 128 + slotf(gjj, li, s_v2b)] = e;
          if (off) {
            cpcw[ni] += cw;
            cpcwl[ni] += cw * logit;
            posbuf[(size_t)gjj * 128 + slotf(gi, li, s_v2b)] = e;
          }
        } else {
          rnsum += e;
          rnmax = fmaxf(rnmax, e);
          if (off) {
            cnsum[ni] += e;
            cnmax[ni] = fmaxf(cnmax[ni], e);
          }
        }
      }
#pragma unroll
      for (int m = 1; m < 16; m <<= 1) {
        rnsum += __shfl_xor(rnsum, m, 64);
        rpcw  += __shfl_xor(rpcw, m, 64);
        rpcwl += __shfl_xor(rpcwl, m, 64);
        rnmax = fmaxf(rnmax, __shfl_xor(rnmax, m, 64));
      }
      if (rr == 0) {
        float4 v; v.x = rnsum; v.y = rpcw; v.z = rpcwl; v.w = rnmax;
        P4[(size_t)gi * 64 + (bj * 2 + wx)] = v;
      }
    }
  }

  if (off) {
#pragma unroll
    for (int ni = 0; ni < 4; ++ni) {
      float cs = cnsum[ni], cm = cnmax[ni], cp = cpcw[ni], cl = cpcwl[ni];
#pragma unroll
      for (int m = 16; m < 64; m <<= 1) {
        cs += __shfl_xor(cs, m, 64);
        cp += __shfl_xor(cp, m, 64);
        cl += __shfl_xor(cl, m, 64);
        cm = fmaxf(cm, __shfl_xor(cm, m, 64));
      }
      if (q == 0) {
        float4 v; v.x = cs; v.y = cp; v.z = cl; v.w = cm;
        P4[(size_t)gj[ni] * 64 + (bi * 2 + wy)] = v;
      }
    }
  }
}

// 512 blocks = 2/CU: 496 off-diagonal tiles + 16 blocks x 2 diagonal tiles.
__global__ __launch_bounds__(256, 2) void main_kernel(
    const unsigned short* __restrict__ Ph, const unsigned short* __restrict__ Pl,
    const int* __restrict__ ov_raw, float4* __restrict__ P4,
    float* __restrict__ posbuf) {
  __shared__ unsigned short Ah[128][64], Al[128][64];
  __shared__ unsigned short Bh[128][64], Bl[128][64];
  __shared__ int s_class2[32], s_v2b[64], s_ov[32];

  decode_ov(ov_raw, s_class2, s_v2b, s_ov);

  const int bid = blockIdx.x;
  if (bid < 496) {
    int idx = bid, bi = 0;
    while (idx >= 31 - bi) { idx -= 31 - bi; ++bi; }
    const int bj = bi + 1 + idx;
    compute_tile(bi, bj, false, Ph, Pl, Ah, Al, Bh, Bl, s_class2, s_v2b, P4,
                 posbuf);
  } else {
    const int d = (bid - 496) * 2;
    compute_tile(d, d, true, Ph, Pl, Ah, Al, Bh, Bl, s_class2, s_v2b, P4,
                 posbuf);
    compute_tile(d + 1, d + 1, true, Ph, Pl, Ah, Al, Bh, Bl, s_class2, s_v2b,
                 P4, posbuf);
  }
}

// 64 blocks x 256, one wave per 16 rows: reduce the 64 partials per row,
// then accuracy/loss; last block writes the 2 outputs.
__global__ __launch_bounds__(256) void finalize_kernel(
    const int* __restrict__ ov_raw, const float4* __restrict__ P4,
    const float* __restrict__ posbuf, float* __restrict__ accum,
    int* __restrict__ counter, float* __restrict__ out) {
  __shared__ int s_class2[32], s_v2b[64], s_ov[32];
  __shared__ float sc[4], sp[4], sl[4];
  decode_ov(ov_raw, s_class2, s_v2b, s_ov);
  __syncthreads();

  const int t = threadIdx.x;
  const int w = t >> 6, lane = t & 63;
  float cnt_acc = 0.f, pos_acc = 0.f, loss_acc = 0.f;
  const int rbase = blockIdx.x * 64 + w * 16;
  for (int i = 0; i < 16; ++i) {
    const int row = rbase + i;
    // reduce 64 partial float4s: sum x,y,z; max w
    float4 p = P4[(size_t)row * 64 + lane];
#pragma unroll
    for (int m = 1; m < 64; m <<= 1) {
      p.x += __shfl_xor(p.x, m, 64);
      p.y += __shfl_xor(p.y, m, 64);
      p.z += __shfl_xor(p.z, m, 64);
      p.w = fmaxf(p.w, __shfl_xor(p.w, m, 64));
    }
    const float nmax = p.w;
    const float2 pv = *(const float2*)&posbuf[(size_t)row * 128 + lane * 2];
    const int c = labf(row, s_class2);
    const int size = (c < 32) ? (s_ov[c] ? 128 : 64) : 64;
    int selfslot;
    if (row < 2048) selfslot = row - (c << 6);
    else selfslot = ((c < 32) ? 64 : 0) + (row - 2048 - (s_v2b[c] << 6));
    const int s0 = lane * 2;
    int h = 0;
    if (s0 < size && s0 != selfslot && pv.x > nmax) h++;
    if (s0 + 1 < size && s0 + 1 != selfslot && pv.y > nmax) h++;
    cnt_acc += (float)h;
    if (lane == 0) {
      loss_acc += logf(p.x) * p.y - p.z;
      pos_acc += (float)(size - 1);
    }
  }
#pragma unroll
  for (int m = 1; m < 64; m <<= 1) {
    cnt_acc += __shfl_xor(cnt_acc, m, 64);
    pos_acc += __shfl_xor(pos_acc, m, 64);
    loss_acc += __shfl_xor(loss_acc, m, 64);
  }
  if (lane == 0) { sc[w] = cnt_acc; sp[w] = pos_acc; sl[w] = loss_acc; }
  __syncthreads();
  if (t == 0) {
    atomicAdd(&accum[0], sc[0] + sc[1] + sc[2] + sc[3]);
    atomicAdd(&accum[1], sp[0] + sp[1] + sp[2] + sp[3]);
    atomicAdd(&accum[2], sl[0] + sl[1] + sl[2] + sl[3]);
    __threadfence();
    const int prev = atomicAdd(counter, 1);
    if (prev == 63) {
      const float c = atomicAdd(&accum[0], 0.0f);
      const float tp = atomicAdd(&accum[1], 0.0f);
      const float lo = atomicAdd(&accum[2], 0.0f);
      out[0] = c / tp;
      out[1] = lo / tp;
    }
  }
}

extern "C" void kernel_launch(void* const* d_in, const int* in_sizes, int n_in,
                              void* d_out, int out_size, void* d_ws,
                              size_t ws_size, hipStream_t stream) {
  const float* f1 = (const float*)d_in[0];
  const float* f2 = (const float*)d_in[1];
  const int* ov = (const int*)d_in[2];
  float* out = (float*)d_out;

  float* wsf = (float*)d_ws;
  int* wsi = (int*)d_ws;
  float* accum  = wsf;                 // 3 floats
  int* counter  = wsi + 3;             // 1 int
  float* posbuf = wsf + 16;            // 4096*128 -> ends at float 524304
  float4* P4    = (float4*)(wsf + 524304);  // 4096*64 float4 = 4 MB
  unsigned short* Ph = (unsigned short*)(wsf + 1572880);
  unsigned short* Pl = Ph + 524288;

  (void)hipMemsetAsync(accum, 0, 16, stream);

  precompute_kernel<<<256, 256, 0, stream>>>(f1, f2, Ph, Pl);
  main_kernel<<<512, 256, 0, stream>>>(Ph, Pl, ov, P4, posbuf);
  finalize_kernel<<<64, 256, 0, stream>>>(ov, P4, posbuf, accum, counter, out);
}

// Round 10
// 110.932 us; speedup vs baseline: 1.1129x; 1.0109x over previous
//
#include <hip/hip_runtime.h>
#include <math.h>

#define TEMP 0.01f

typedef __attribute__((ext_vector_type(8))) short short8;
typedef __attribute__((ext_vector_type(4))) float f32x4;
typedef __attribute__((ext_vector_type(8))) unsigned short ushort8_t;

// ---------------------------------------------------------------------------
// ws layout (floats from base):
//   accum  f32[3] @ 0, counter int @ 3          (zeroed by precompute thread 0)
//   posbuf f32[4096*128] @ 16                   (per-row positive exp slots)
//   P4     float4[4096*64] @ float 524304       (per-row partial stats:
//            [row][other_tile*2 + half] = {nsum, pcw, pcwl, nmax};
//            every slot written by exactly one wave -> no init, NO ATOMICS)
//   Ph     ushort[4096*128] @ float 1572880     (bf16-hi plane, swizzled)
//   Pl     ushort[4096*128] after Ph            (bf16-lo plane)
// total ~8.4 MB.
// ---------------------------------------------------------------------------

__device__ __forceinline__ unsigned bf16_hi_bits(float x) {
  unsigned u = __float_as_uint(x);
  return (u + 0x7FFFu + ((u >> 16) & 1u)) >> 16;  // RNE to bf16
}

struct HL { unsigned short h, l; };

__device__ __forceinline__ HL split1(float x) {
  unsigned hb = bf16_hi_bits(x);
  float hf = __uint_as_float(hb << 16);
  unsigned lb = bf16_hi_bits(x - hf);
  HL r;
  r.h = (unsigned short)hb;
  r.l = (unsigned short)lb;
  return r;
}

__device__ __forceinline__ void decode_ov(const int* __restrict__ ov_raw,
                                          int* s_class2, int* s_v2b,
                                          int* s_ov) {
  const int t = threadIdx.x;
  if (t < 64) {
    int v = (t < 32) ? ov_raw[t] : 0;
    bool valid = (t >= 32) || (v == 0) || (v == 1);
    unsigned long long okmask = __ballot(valid);
    bool as_int = (okmask == ~0ull);
    s_v2b[t] = 0;
    if (t < 32) {
      int o = as_int ? v : (((const unsigned char*)ov_raw)[t] ? 1 : 0);
      s_ov[t] = o;
      unsigned long long nz = __ballot((t < 32) && !o);
      int cum = __popcll(nz & ((1ull << t) - 1ull));
      int c2 = o ? t : 32 + cum;
      s_class2[t] = c2;
      s_v2b[c2] = t;
    }
  }
}

__device__ __forceinline__ int labf(int g, const int* s_class2) {
  return (g < 2048) ? (g >> 6) : s_class2[(g - 2048) >> 6];
}

__device__ __forceinline__ int slotf(int g, int cls, const int* s_v2b) {
  if (g < 2048) return g - (cls << 6);
  return ((cls < 32) ? 64 : 0) + (g - 2048 - (s_v2b[cls] << 6));
}

// ---------------------------------------------------------------------------
// Precompute: bf16 hi/lo planes with swizzle baked in; thread 0 of block 0
// also zeroes accum/counter (replaces the memset dispatch).
// ---------------------------------------------------------------------------
__global__ __launch_bounds__(256) void precompute_kernel(
    const float* __restrict__ f1, const float* __restrict__ f2,
    unsigned short* __restrict__ Ph, unsigned short* __restrict__ Pl,
    float* __restrict__ accum, int* __restrict__ counter) {
  if (blockIdx.x == 0 && threadIdx.x == 0) {
    accum[0] = 0.f; accum[1] = 0.f; accum[2] = 0.f; *counter = 0;
  }
  const int u = blockIdx.x * 256 + threadIdx.x;  // 65536 threads
  const int row = u >> 4;
  const int gid = u & 15;          // kc*8 + P
  const int kc = gid >> 3, P = gid & 7;
  const int k = kc * 64 + (P ^ (row & 7)) * 8;
  const float* src = (row < 2048) ? (f1 + (size_t)row * 128)
                                  : (f2 + (size_t)(row - 2048) * 128);
  const float4 a = *(const float4*)(src + k);
  const float4 b = *(const float4*)(src + k + 4);
  ushort8_t hi, lo;
  HL s;
  s = split1(a.x); hi.s0 = s.h; lo.s0 = s.l;
  s = split1(a.y); hi.s1 = s.h; lo.s1 = s.l;
  s = split1(a.z); hi.s2 = s.h; lo.s2 = s.l;
  s = split1(a.w); hi.s3 = s.h; lo.s3 = s.l;
  s = split1(b.x); hi.s4 = s.h; lo.s4 = s.l;
  s = split1(b.y); hi.s5 = s.h; lo.s5 = s.l;
  s = split1(b.z); hi.s6 = s.h; lo.s6 = s.l;
  s = split1(b.w); hi.s7 = s.h; lo.s7 = s.l;
  *(ushort8_t*)&Ph[(size_t)row * 128 + gid * 8] = hi;
  *(ushort8_t*)&Pl[(size_t)row * 128 + gid * 8] = lo;
}

// ---------------------------------------------------------------------------
// One 128x128 tile — R9 proven (bit-exact, no atomics).
// ---------------------------------------------------------------------------
__device__ __forceinline__ void compute_tile(
    int bi, int bj, bool diag,
    const unsigned short* __restrict__ Ph, const unsigned short* __restrict__ Pl,
    unsigned short (*Ah)[64], unsigned short (*Al)[64],
    unsigned short (*Bh)[64], unsigned short (*Bl)[64],
    const int* s_class2, const int* s_v2b,
    float4* __restrict__ P4, float* __restrict__ posbuf) {
  const int ibase = bi * 128, jbase = bj * 128;
  const int t = threadIdx.x;
  const int l = t & 63;
  const int wid = t >> 6;
  const int wy = wid >> 1, wx = wid & 1;
  const int rr = l & 15;
  const int q = l >> 4;
  const int sw = l & 7;

  f32x4 acc[4][4];
#pragma unroll
  for (int mi = 0; mi < 4; ++mi)
#pragma unroll
    for (int ni = 0; ni < 4; ++ni) acc[mi][ni] = (f32x4)0.0f;

  const int gg = t & 7;    // physical granule
  const int r0 = t >> 3;   // row 0..31 per pass

  for (int kc = 0; kc < 2; ++kc) {
    __syncthreads();
#pragma unroll
    for (int p = 0; p < 4; ++p) {
      const int r = r0 + 32 * p;
      const size_t arec = (size_t)(ibase + r) * 128 + kc * 64 + gg * 8;
      const ushort8_t vah = *(const ushort8_t*)&Ph[arec];
      const ushort8_t val = *(const ushort8_t*)&Pl[arec];
      *(ushort8_t*)&Ah[r][gg * 8] = vah;
      *(ushort8_t*)&Al[r][gg * 8] = val;
      if (!diag) {
        const size_t brec = (size_t)(jbase + r) * 128 + kc * 64 + gg * 8;
        const ushort8_t vbh = *(const ushort8_t*)&Ph[brec];
        const ushort8_t vbl = *(const ushort8_t*)&Pl[brec];
        *(ushort8_t*)&Bh[r][gg * 8] = vbh;
        *(ushort8_t*)&Bl[r][gg * 8] = vbl;
      }
    }
    __syncthreads();

#pragma unroll
    for (int s = 0; s < 2; ++s) {
      const int pb = ((((s << 2) | q)) ^ sw) << 3;
      short8 afh[4], afl[4], bfh[4], bfl[4];
#pragma unroll
      for (int mi = 0; mi < 4; ++mi) {
        const int ar = wy * 64 + mi * 16 + rr;
        afh[mi] = *(const short8*)&Ah[ar][pb];
        afl[mi] = *(const short8*)&Al[ar][pb];
        const int br = wx * 64 + mi * 16 + rr;
        bfh[mi] = diag ? *(const short8*)&Ah[br][pb]
                       : *(const short8*)&Bh[br][pb];
        bfl[mi] = diag ? *(const short8*)&Al[br][pb]
                       : *(const short8*)&Bl[br][pb];
      }
#pragma unroll
      for (int mi = 0; mi < 4; ++mi)
#pragma unroll
        for (int ni = 0; ni < 4; ++ni) {
          acc[mi][ni] = __builtin_amdgcn_mfma_f32_16x16x32_bf16(
              afh[mi], bfh[ni], acc[mi][ni], 0, 0, 0);
          acc[mi][ni] = __builtin_amdgcn_mfma_f32_16x16x32_bf16(
              afh[mi], bfl[ni], acc[mi][ni], 0, 0, 0);
          acc[mi][ni] = __builtin_amdgcn_mfma_f32_16x16x32_bf16(
              afl[mi], bfh[ni], acc[mi][ni], 0, 0, 0);
        }
    }
  }

  // ---------------- fused epilogue: partial stores, no atomics ------------
  const bool off = !diag;
  const float cw = ((ibase < 2048) != (jbase < 2048)) ? 0.5f : 1.0f;
  int gj[4], lj[4];
#pragma unroll
  for (int ni = 0; ni < 4; ++ni) {
    gj[ni] = jbase + wx * 64 + ni * 16 + rr;
    lj[ni] = labf(gj[ni], s_class2);
  }

  float cnsum[4], cnmax[4], cpcw[4], cpcwl[4];
#pragma unroll
  for (int ni = 0; ni < 4; ++ni) {
    cnsum[ni] = 0.f; cnmax[ni] = 0.f; cpcw[ni] = 0.f; cpcwl[ni] = 0.f;
  }

#pragma unroll
  for (int mi = 0; mi < 4; ++mi) {
#pragma unroll
    for (int reg = 0; reg < 4; ++reg) {
      const int gi = ibase + wy * 64 + mi * 16 + q * 4 + reg;
      const int li = labf(gi, s_class2);
      float rnsum = 0.f, rnmax = 0.f, rpcw = 0.f, rpcwl = 0.f;
#pragma unroll
      for (int ni = 0; ni < 4; ++ni) {
        const int gjj = gj[ni];
        if (gi == gjj) continue;
        const float logit = acc[mi][ni][reg] * TEMP;
        const float e = __expf(logit);
        if (li == lj[ni]) {
          rpcw += cw;
          rpcwl += cw * logit;
          posbuf[(size_t)gi * 128 + slotf(gjj, li, s_v2b)] = e;
          if (off) {
            cpcw[ni] += cw;
            cpcwl[ni] += cw * logit;
            posbuf[(size_t)gjj * 128 + slotf(gi, li, s_v2b)] = e;
          }
        } else {
          rnsum += e;
          rnmax = fmaxf(rnmax, e);
          if (off) {
            cnsum[ni] += e;
            cnmax[ni] = fmaxf(cnmax[ni], e);
          }
        }
      }
#pragma unroll
      for (int m = 1; m < 16; m <<= 1) {
        rnsum += __shfl_xor(rnsum, m, 64);
        rpcw  += __shfl_xor(rpcw, m, 64);
        rpcwl += __shfl_xor(rpcwl, m, 64);
        rnmax = fmaxf(rnmax, __shfl_xor(rnmax, m, 64));
      }
      if (rr == 0) {
        float4 v; v.x = rnsum; v.y = rpcw; v.z = rpcwl; v.w = rnmax;
        P4[(size_t)gi * 64 + (bj * 2 + wx)] = v;
      }
    }
  }

  if (off) {
#pragma unroll
    for (int ni = 0; ni < 4; ++ni) {
      float cs = cnsum[ni], cm = cnmax[ni], cp = cpcw[ni], cl = cpcwl[ni];
#pragma unroll
      for (int m = 16; m < 64; m <<= 1) {
        cs += __shfl_xor(cs, m, 64);
        cp += __shfl_xor(cp, m, 64);
        cl += __shfl_xor(cl, m, 64);
        cm = fmaxf(cm, __shfl_xor(cm, m, 64));
      }
      if (q == 0) {
        float4 v; v.x = cs; v.y = cp; v.z = cl; v.w = cm;
        P4[(size_t)gj[ni] * 64 + (bi * 2 + wy)] = v;
      }
    }
  }
}

// 512 blocks = 2/CU: 496 off-diagonal tiles + 16 blocks x 2 diagonal tiles.
__global__ __launch_bounds__(256, 2) void main_kernel(
    const unsigned short* __restrict__ Ph, const unsigned short* __restrict__ Pl,
    const int* __restrict__ ov_raw, float4* __restrict__ P4,
    float* __restrict__ posbuf) {
  __shared__ unsigned short Ah[128][64], Al[128][64];
  __shared__ unsigned short Bh[128][64], Bl[128][64];
  __shared__ int s_class2[32], s_v2b[64], s_ov[32];

  decode_ov(ov_raw, s_class2, s_v2b, s_ov);

  const int bid = blockIdx.x;
  if (bid < 496) {
    int idx = bid, bi = 0;
    while (idx >= 31 - bi) { idx -= 31 - bi; ++bi; }
    const int bj = bi + 1 + idx;
    compute_tile(bi, bj, false, Ph, Pl, Ah, Al, Bh, Bl, s_class2, s_v2b, P4,
                 posbuf);
  } else {
    const int d = (bid - 496) * 2;
    compute_tile(d, d, true, Ph, Pl, Ah, Al, Bh, Bl, s_class2, s_v2b, P4,
                 posbuf);
    compute_tile(d + 1, d + 1, true, Ph, Pl, Ah, Al, Bh, Bl, s_class2, s_v2b,
                 P4, posbuf);
  }
}

// 256 blocks x 256, one wave per 4 rows; last block writes the 2 outputs.
__global__ __launch_bounds__(256) void finalize_kernel(
    const int* __restrict__ ov_raw, const float4* __restrict__ P4,
    const float* __restrict__ posbuf, float* __restrict__ accum,
    int* __restrict__ counter, float* __restrict__ out) {
  __shared__ int s_class2[32], s_v2b[64], s_ov[32];
  __shared__ float sc[4], sp[4], sl[4];
  decode_ov(ov_raw, s_class2, s_v2b, s_ov);
  __syncthreads();

  const int t = threadIdx.x;
  const int w = t >> 6, lane = t & 63;
  float cnt_acc = 0.f, pos_acc = 0.f, loss_acc = 0.f;
  const int rbase = blockIdx.x * 16 + w * 4;
  for (int i = 0; i < 4; ++i) {
    const int row = rbase + i;
    // reduce 64 partial float4s: sum x,y,z; max w
    float4 p = P4[(size_t)row * 64 + lane];
#pragma unroll
    for (int m = 1; m < 64; m <<= 1) {
      p.x += __shfl_xor(p.x, m, 64);
      p.y += __shfl_xor(p.y, m, 64);
      p.z += __shfl_xor(p.z, m, 64);
      p.w = fmaxf(p.w, __shfl_xor(p.w, m, 64));
    }
    const float nmax = p.w;
    const float2 pv = *(const float2*)&posbuf[(size_t)row * 128 + lane * 2];
    const int c = labf(row, s_class2);
    const int size = (c < 32) ? (s_ov[c] ? 128 : 64) : 64;
    int selfslot;
    if (row < 2048) selfslot = row - (c << 6);
    else selfslot = ((c < 32) ? 64 : 0) + (row - 2048 - (s_v2b[c] << 6));
    const int s0 = lane * 2;
    int h = 0;
    if (s0 < size && s0 != selfslot && pv.x > nmax) h++;
    if (s0 + 1 < size && s0 + 1 != selfslot && pv.y > nmax) h++;
    cnt_acc += (float)h;
    if (lane == 0) {
      loss_acc += logf(p.x) * p.y - p.z;
      pos_acc += (float)(size - 1);
    }
  }
#pragma unroll
  for (int m = 1; m < 64; m <<= 1) {
    cnt_acc += __shfl_xor(cnt_acc, m, 64);
    pos_acc += __shfl_xor(pos_acc, m, 64);
    loss_acc += __shfl_xor(loss_acc, m, 64);
  }
  if (lane == 0) { sc[w] = cnt_acc; sp[w] = pos_acc; sl[w] = loss_acc; }
  __syncthreads();
  if (t == 0) {
    atomicAdd(&accum[0], sc[0] + sc[1] + sc[2] + sc[3]);
    atomicAdd(&accum[1], sp[0] + sp[1] + sp[2] + sp[3]);
    atomicAdd(&accum[2], sl[0] + sl[1] + sl[2] + sl[3]);
    __threadfence();
    const int prev = atomicAdd(counter, 1);
    if (prev == 255) {
      const float c = atomicAdd(&accum[0], 0.0f);
      const float tp = atomicAdd(&accum[1], 0.0f);
      const float lo = atomicAdd(&accum[2], 0.0f);
      out[0] = c / tp;
      out[1] = lo / tp;
    }
  }
}

extern "C" void kernel_launch(void* const* d_in, const int* in_sizes, int n_in,
                              void* d_out, int out_size, void* d_ws,
                              size_t ws_size, hipStream_t stream) {
  const float* f1 = (const float*)d_in[0];
  const float* f2 = (const float*)d_in[1];
  const int* ov = (const int*)d_in[2];
  float* out = (float*)d_out;

  float* wsf = (float*)d_ws;
  int* wsi = (int*)d_ws;
  float* accum  = wsf;                 // 3 floats
  int* counter  = wsi + 3;             // 1 int
  float* posbuf = wsf + 16;            // 4096*128 -> ends at float 524304
  float4* P4    = (float4*)(wsf + 524304);  // 4096*64 float4 = 4 MB
  unsigned short* Ph = (unsigned short*)(wsf + 1572880);
  unsigned short* Pl = Ph + 524288;

  precompute_kernel<<<256, 256, 0, stream>>>(f1, f2, Ph, Pl, accum, counter);
  main_kernel<<<512, 256, 0, stream>>>(Ph, Pl, ov, P4, posbuf);
  finalize_kernel<<<256, 256, 0, stream>>>(ov, P4, posbuf, accum, counter,
                                           out);
}

// Round 11
// 106.386 us; speedup vs baseline: 1.1604x; 1.0427x over previous
//
#include <hip/hip_runtime.h>
#include <math.h>

#define TEMP 0.01f

typedef __attribute__((ext_vector_type(8))) short short8;
typedef __attribute__((ext_vector_type(4))) float f32x4;
typedef __attribute__((ext_vector_type(8))) unsigned short ushort8_t;

// ---------------------------------------------------------------------------
// ws layout (floats from base):
//   accum  f32[3] @ 0, counter int @ 3          (zeroed by precompute thread 0)
//   posbuf f32[4096*128] @ 16
//   P4     float4[4096*64] @ float 524304       ({nsum, 0, pcwl, nmax};
//            every slot written by exactly one thread -> no init, NO ATOMICS)
//   Ph     ushort[4096*128] @ float 1572880     (bf16-hi plane, swizzled)
//   Pl     ushort[4096*128] after Ph            (bf16-lo plane)
// ---------------------------------------------------------------------------

__device__ __forceinline__ unsigned bf16_hi_bits(float x) {
  unsigned u = __float_as_uint(x);
  return (u + 0x7FFFu + ((u >> 16) & 1u)) >> 16;  // RNE to bf16
}

struct HL { unsigned short h, l; };

__device__ __forceinline__ HL split1(float x) {
  unsigned hb = bf16_hi_bits(x);
  float hf = __uint_as_float(hb << 16);
  unsigned lb = bf16_hi_bits(x - hf);
  HL r;
  r.h = (unsigned short)hb;
  r.l = (unsigned short)lb;
  return r;
}

__device__ __forceinline__ void decode_ov(const int* __restrict__ ov_raw,
                                          int* s_class2, int* s_v2b,
                                          int* s_ov) {
  const int t = threadIdx.x;
  if (t < 64) {
    int v = (t < 32) ? ov_raw[t] : 0;
    bool valid = (t >= 32) || (v == 0) || (v == 1);
    unsigned long long okmask = __ballot(valid);
    bool as_int = (okmask == ~0ull);
    s_v2b[t] = 0;
    if (t < 32) {
      int o = as_int ? v : (((const unsigned char*)ov_raw)[t] ? 1 : 0);
      s_ov[t] = o;
      unsigned long long nz = __ballot((t < 32) && !o);
      int cum = __popcll(nz & ((1ull << t) - 1ull));
      int c2 = o ? t : 32 + cum;
      s_class2[t] = c2;
      s_v2b[c2] = t;
    }
  }
}

__device__ __forceinline__ int labf(int g, const int* s_class2) {
  return (g < 2048) ? (g >> 6) : s_class2[(g - 2048) >> 6];
}

__device__ __forceinline__ int slotf(int g, int cls, const int* s_v2b) {
  if (g < 2048) return g - (cls << 6);
  return ((cls < 32) ? 64 : 0) + (g - 2048 - (s_v2b[cls] << 6));
}

// ---------------------------------------------------------------------------
// Precompute: bf16 hi/lo planes, swizzle baked in; block 0 zeroes accum.
// ---------------------------------------------------------------------------
__global__ __launch_bounds__(256) void precompute_kernel(
    const float* __restrict__ f1, const float* __restrict__ f2,
    unsigned short* __restrict__ Ph, unsigned short* __restrict__ Pl,
    float* __restrict__ accum, int* __restrict__ counter) {
  if (blockIdx.x == 0 && threadIdx.x == 0) {
    accum[0] = 0.f; accum[1] = 0.f; accum[2] = 0.f; *counter = 0;
  }
  const int u = blockIdx.x * 256 + threadIdx.x;  // 65536 threads
  const int row = u >> 4;
  const int gid = u & 15;          // kc*8 + P
  const int kc = gid >> 3, P = gid & 7;
  const int k = kc * 64 + (P ^ (row & 7)) * 8;
  const float* src = (row < 2048) ? (f1 + (size_t)row * 128)
                                  : (f2 + (size_t)(row - 2048) * 128);
  const float4 a = *(const float4*)(src + k);
  const float4 b = *(const float4*)(src + k + 4);
  ushort8_t hi, lo;
  HL s;
  s = split1(a.x); hi.s0 = s.h; lo.s0 = s.l;
  s = split1(a.y); hi.s1 = s.h; lo.s1 = s.l;
  s = split1(a.z); hi.s2 = s.h; lo.s2 = s.l;
  s = split1(a.w); hi.s3 = s.h; lo.s3 = s.l;
  s = split1(b.x); hi.s4 = s.h; lo.s4 = s.l;
  s = split1(b.y); hi.s5 = s.h; lo.s5 = s.l;
  s = split1(b.z); hi.s6 = s.h; lo.s6 = s.l;
  s = split1(b.w); hi.s7 = s.h; lo.s7 = s.l;
  *(ushort8_t*)&Ph[(size_t)row * 128 + gid * 8] = hi;
  *(ushort8_t*)&Pl[(size_t)row * 128 + gid * 8] = lo;
}

// ---------------------------------------------------------------------------
// One 128x128 tile — proven bit-exact K-loop; epilogue reductions via LDS
// transpose (overlaid on the tile buffers), NO shuffle chains, NO atomics.
// ---------------------------------------------------------------------------
__device__ __forceinline__ void compute_tile(
    int bi, int bj, bool diag,
    const unsigned short* __restrict__ Ph, const unsigned short* __restrict__ Pl,
    unsigned short (*Ah)[64], unsigned short (*Al)[64],
    unsigned short (*Bh)[64], unsigned short (*Bl)[64],
    const int* s_class2, const int* s_v2b,
    float4* __restrict__ P4, float* __restrict__ posbuf) {
  const int ibase = bi * 128, jbase = bj * 128;
  const int t = threadIdx.x;
  const int l = t & 63;
  const int wid = t >> 6;
  const int wy = wid >> 1, wx = wid & 1;
  const int rr = l & 15;
  const int q = l >> 4;
  const int sw = l & 7;

  f32x4 acc[4][4];
#pragma unroll
  for (int mi = 0; mi < 4; ++mi)
#pragma unroll
    for (int ni = 0; ni < 4; ++ni) acc[mi][ni] = (f32x4)0.0f;

  const int gg = t & 7;    // physical granule
  const int r0 = t >> 3;   // row 0..31 per pass

  for (int kc = 0; kc < 2; ++kc) {
    __syncthreads();  // protects LDS from prior readers (K-loop & epilogue)
#pragma unroll
    for (int p = 0; p < 4; ++p) {
      const int r = r0 + 32 * p;
      const size_t arec = (size_t)(ibase + r) * 128 + kc * 64 + gg * 8;
      const ushort8_t vah = *(const ushort8_t*)&Ph[arec];
      const ushort8_t val = *(const ushort8_t*)&Pl[arec];
      *(ushort8_t*)&Ah[r][gg * 8] = vah;
      *(ushort8_t*)&Al[r][gg * 8] = val;
      if (!diag) {
        const size_t brec = (size_t)(jbase + r) * 128 + kc * 64 + gg * 8;
        const ushort8_t vbh = *(const ushort8_t*)&Ph[brec];
        const ushort8_t vbl = *(const ushort8_t*)&Pl[brec];
        *(ushort8_t*)&Bh[r][gg * 8] = vbh;
        *(ushort8_t*)&Bl[r][gg * 8] = vbl;
      }
    }
    __syncthreads();

#pragma unroll
    for (int s = 0; s < 2; ++s) {
      const int pb = ((((s << 2) | q)) ^ sw) << 3;
      short8 afh[4], afl[4], bfh[4], bfl[4];
#pragma unroll
      for (int mi = 0; mi < 4; ++mi) {
        const int ar = wy * 64 + mi * 16 + rr;
        afh[mi] = *(const short8*)&Ah[ar][pb];
        afl[mi] = *(const short8*)&Al[ar][pb];
        const int br = wx * 64 + mi * 16 + rr;
        bfh[mi] = diag ? *(const short8*)&Ah[br][pb]
                       : *(const short8*)&Bh[br][pb];
        bfl[mi] = diag ? *(const short8*)&Al[br][pb]
                       : *(const short8*)&Bl[br][pb];
      }
#pragma unroll
      for (int mi = 0; mi < 4; ++mi)
#pragma unroll
        for (int ni = 0; ni < 4; ++ni) {
          acc[mi][ni] = __builtin_amdgcn_mfma_f32_16x16x32_bf16(
              afh[mi], bfh[ni], acc[mi][ni], 0, 0, 0);
          acc[mi][ni] = __builtin_amdgcn_mfma_f32_16x16x32_bf16(
              afh[mi], bfl[ni], acc[mi][ni], 0, 0, 0);
          acc[mi][ni] = __builtin_amdgcn_mfma_f32_16x16x32_bf16(
              afl[mi], bfh[ni], acc[mi][ni], 0, 0, 0);
        }
    }
  }

  // -------- epilogue: LDS-transpose reductions (no shuffles, no atomics) ---
  const bool off = !diag;
  const float cw = ((ibase < 2048) != (jbase < 2048)) ? 0.5f : 1.0f;

  // LDS overlays (tile buffers are dead after the last MFMA read + barrier)
  float* RowPn = (float*)&Ah[0][0];   // [ (g*4+wid)*64 + lane ]  (4096 f)
  float* RowPl = (float*)&Al[0][0];
  float* RowPm = (float*)&Bh[0][0];
  float* ColPn = (float*)&Bl[0][0];   // [ (ni*4+wid)*64 + lane ] (1024 f)
  float* ColPl = ColPn + 1024;
  float* ColPm = ColPn + 2048;

  int gj[4], lj[4];
#pragma unroll
  for (int ni = 0; ni < 4; ++ni) {
    gj[ni] = jbase + wx * 64 + ni * 16 + rr;
    lj[ni] = labf(gj[ni], s_class2);
  }

  float cnsum[4], cnmax[4], clsum[4];
#pragma unroll
  for (int ni = 0; ni < 4; ++ni) {
    cnsum[ni] = 0.f; cnmax[ni] = 0.f; clsum[ni] = 0.f;
  }

  __syncthreads();  // all waves done reading tile LDS before overlay writes

#pragma unroll
  for (int mi = 0; mi < 4; ++mi) {
#pragma unroll
    for (int reg = 0; reg < 4; ++reg) {
      const int gi = ibase + wy * 64 + mi * 16 + q * 4 + reg;
      const int li = labf(gi, s_class2);
      float rn = 0.f, rl = 0.f, rm = 0.f;
#pragma unroll
      for (int ni = 0; ni < 4; ++ni) {
        const int gjj = gj[ni];
        if (gi == gjj) continue;
        const float logit = acc[mi][ni][reg] * TEMP;
        const float e = __expf(logit);
        if (li == lj[ni]) {
          rl += logit;
          posbuf[(size_t)gi * 128 + slotf(gjj, li, s_v2b)] = e;
          if (off) {
            clsum[ni] += logit;
            posbuf[(size_t)gjj * 128 + slotf(gi, li, s_v2b)] = e;
          }
        } else {
          rn += e;
          rm = fmaxf(rm, e);
          if (off) {
            cnsum[ni] += e;
            cnmax[ni] = fmaxf(cnmax[ni], e);
          }
        }
      }
      const int widx = ((mi * 4 + reg) * 4 + wid) * 64 + l;
      RowPn[widx] = rn;
      RowPl[widx] = rl;
      RowPm[widx] = rm;
    }
  }
  if (off) {
#pragma unroll
    for (int ni = 0; ni < 4; ++ni) {
      const int widx = (ni * 4 + wid) * 64 + l;
      ColPn[widx] = cnsum[ni];
      ColPl[widx] = clsum[ni];
      ColPm[widx] = cnmax[ni];
    }
  }
  __syncthreads();

  // phase 2a: row reduce — thread t owns (row r = t>>1, col-half h = t&1)
  {
    const int r = t >> 1, h = t & 1;
    const int g = (((r >> 4) & 3) * 4) + (r & 3);      // mi*4+reg
    const int w2 = (r >> 6) * 2 + h;                   // wy*2+wx
    const int base = (g * 4 + w2) * 64 + ((r >> 2) & 3) * 16;
    const float4* pn = (const float4*)&RowPn[base];
    const float4* pl = (const float4*)&RowPl[base];
    const float4* pm = (const float4*)&RowPm[base];
    float ns = 0.f, ls = 0.f, nm = 0.f;
#pragma unroll
    for (int i = 0; i < 4; ++i) {
      const float4 a = pn[i], b = pl[i], c = pm[i];
      ns += a.x + a.y + a.z + a.w;
      ls += b.x + b.y + b.z + b.w;
      nm = fmaxf(nm, fmaxf(fmaxf(c.x, c.y), fmaxf(c.z, c.w)));
    }
    float4 v; v.x = ns; v.y = 0.f; v.z = cw * ls; v.w = nm;
    P4[(size_t)(ibase + r) * 64 + (bj * 2 + h)] = v;
  }

  // phase 2b: col reduce (off-diag only) — thread t owns (col c=t>>1, wy=t&1)
  if (off) {
    const int c = t >> 1, hy = t & 1;
    const int w2 = hy * 2 + (c >> 6);                  // wy*2+wx
    const int base = (((c >> 4) & 3) * 4 + w2) * 64 + (c & 15);
    float ns = 0.f, ls = 0.f, nm = 0.f;
#pragma unroll
    for (int q4 = 0; q4 < 4; ++q4) {
      const int idx = base + q4 * 16;
      ns += ColPn[idx];
      ls += ColPl[idx];
      nm = fmaxf(nm, ColPm[idx]);
    }
    float4 v; v.x = ns; v.y = 0.f; v.z = cw * ls; v.w = nm;
    P4[(size_t)(jbase + c) * 64 + (bi * 2 + hy)] = v;
  }
}

// 512 blocks = 2/CU: 496 off-diagonal tiles + 16 blocks x 2 diagonal tiles.
__global__ __launch_bounds__(256, 2) void main_kernel(
    const unsigned short* __restrict__ Ph, const unsigned short* __restrict__ Pl,
    const int* __restrict__ ov_raw, float4* __restrict__ P4,
    float* __restrict__ posbuf) {
  __shared__ unsigned short Ah[128][64], Al[128][64];
  __shared__ unsigned short Bh[128][64], Bl[128][64];
  __shared__ int s_class2[32], s_v2b[64], s_ov[32];

  decode_ov(ov_raw, s_class2, s_v2b, s_ov);

  const int bid = blockIdx.x;
  if (bid < 496) {
    int idx = bid, bi = 0;
    while (idx >= 31 - bi) { idx -= 31 - bi; ++bi; }
    const int bj = bi + 1 + idx;
    compute_tile(bi, bj, false, Ph, Pl, Ah, Al, Bh, Bl, s_class2, s_v2b, P4,
                 posbuf);
  } else {
    const int d = (bid - 496) * 2;
    compute_tile(d, d, true, Ph, Pl, Ah, Al, Bh, Bl, s_class2, s_v2b, P4,
                 posbuf);
    compute_tile(d + 1, d + 1, true, Ph, Pl, Ah, Al, Bh, Bl, s_class2, s_v2b,
                 P4, posbuf);
  }
}

// 256 blocks x 256, one wave per 4 rows; last block writes the 2 outputs.
// pcw is analytic: 95 if the row's class spans both views, else 63.
__global__ __launch_bounds__(256) void finalize_kernel(
    const int* __restrict__ ov_raw, const float4* __restrict__ P4,
    const float* __restrict__ posbuf, float* __restrict__ accum,
    int* __restrict__ counter, float* __restrict__ out) {
  __shared__ int s_class2[32], s_v2b[64], s_ov[32];
  __shared__ float sc[4], sp[4], sl[4];
  decode_ov(ov_raw, s_class2, s_v2b, s_ov);
  __syncthreads();

  const int t = threadIdx.x;
  const int w = t >> 6, lane = t & 63;
  float cnt_acc = 0.f, pos_acc = 0.f, loss_acc = 0.f;
  const int rbase = blockIdx.x * 16 + w * 4;
  for (int i = 0; i < 4; ++i) {
    const int row = rbase + i;
    float4 p = P4[(size_t)row * 64 + lane];
#pragma unroll
    for (int m = 1; m < 64; m <<= 1) {
      p.x += __shfl_xor(p.x, m, 64);
      p.z += __shfl_xor(p.z, m, 64);
      p.w = fmaxf(p.w, __shfl_xor(p.w, m, 64));
    }
    const float nmax = p.w;
    const float2 pv = *(const float2*)&posbuf[(size_t)row * 128 + lane * 2];
    const int c = labf(row, s_class2);
    const bool both = (row < 2048) ? (s_ov[c] != 0) : (c < 32);
    const int size = both ? 128 : 64;
    int selfslot;
    if (row < 2048) selfslot = row - (c << 6);
    else selfslot = ((c < 32) ? 64 : 0) + (row - 2048 - (s_v2b[c] << 6));
    const int s0 = lane * 2;
    int h = 0;
    if (s0 < size && s0 != selfslot && pv.x > nmax) h++;
    if (s0 + 1 < size && s0 + 1 != selfslot && pv.y > nmax) h++;
    cnt_acc += (float)h;
    if (lane == 0) {
      const float pcw = both ? 95.f : 63.f;
      loss_acc += logf(p.x) * pcw - p.z;
      pos_acc += (float)(size - 1);
    }
  }
#pragma unroll
  for (int m = 1; m < 64; m <<= 1) {
    cnt_acc += __shfl_xor(cnt_acc, m, 64);
    pos_acc += __shfl_xor(pos_acc, m, 64);
    loss_acc += __shfl_xor(loss_acc, m, 64);
  }
  if (lane == 0) { sc[w] = cnt_acc; sp[w] = pos_acc; sl[w] = loss_acc; }
  __syncthreads();
  if (t == 0) {
    atomicAdd(&accum[0], sc[0] + sc[1] + sc[2] + sc[3]);
    atomicAdd(&accum[1], sp[0] + sp[1] + sp[2] + sp[3]);
    atomicAdd(&accum[2], sl[0] + sl[1] + sl[2] + sl[3]);
    __threadfence();
    const int prev = atomicAdd(counter, 1);
    if (prev == 255) {
      const float c = atomicAdd(&accum[0], 0.0f);
      const float tp = atomicAdd(&accum[1], 0.0f);
      const float lo = atomicAdd(&accum[2], 0.0f);
      out[0] = c / tp;
      out[1] = lo / tp;
    }
  }
}

extern "C" void kernel_launch(void* const* d_in, const int* in_sizes, int n_in,
                              void* d_out, int out_size, void* d_ws,
                              size_t ws_size, hipStream_t stream) {
  const float* f1 = (const float*)d_in[0];
  const float* f2 = (const float*)d_in[1];
  const int* ov = (const int*)d_in[2];
  float* out = (float*)d_out;

  float* wsf = (float*)d_ws;
  int* wsi = (int*)d_ws;
  float* accum  = wsf;                 // 3 floats
  int* counter  = wsi + 3;             // 1 int
  float* posbuf = wsf + 16;            // 4096*128 -> ends at float 524304
  float4* P4    = (float4*)(wsf + 524304);  // 4096*64 float4 = 4 MB
  unsigned short* Ph = (unsigned short*)(wsf + 1572880);
  unsigned short* Pl = Ph + 524288;

  precompute_kernel<<<256, 256, 0, stream>>>(f1, f2, Ph, Pl, accum, counter);
  main_kernel<<<512, 256, 0, stream>>>(Ph, Pl, ov, P4, posbuf);
  finalize_kernel<<<256, 256, 0, stream>>>(ov, P4, posbuf, accum, counter,
                                           out);
}